// Round 13
// baseline (92.163 us; speedup 1.0000x reference)
//
#include <hip/hip_runtime.h>

#define KE_KCAL 332.0637f

constexpr int N_ATOMS = 6144;
constexpr int NTILE = 1200;             // triangular 256x64 tiles
constexpr int NPAIRB = 2400;            // 2 sub-blocks (32-j) per tile
constexpr int NPRED = 384;              // pred blocks (16 atoms each)

// ---------------- kernel A: pred + per-block sums + pack --------------------
// 384 blocks x 256 thr, 4 atoms/wave (proven body). Plain stores only.
__global__ __launch_bounds__(256) void pred_kernel(
    const float* __restrict__ f, const int* __restrict__ z,
    const float* __restrict__ w, const float* __restrict__ ztab,
    const float* __restrict__ xyz,
    float* __restrict__ qpart, float4* __restrict__ xqp)
{
    int t = threadIdx.x, b = blockIdx.x;
    int lane = t & 63, wid = t >> 6;

    int base = b * 16 + wid * 4;
    const float2* f2 = (const float2*)f;
    float2 wv = ((const float2*)w)[lane];
    float2 v0 = f2[(size_t)(base + 0) * 64 + lane];
    float2 v1 = f2[(size_t)(base + 1) * 64 + lane];
    float2 v2 = f2[(size_t)(base + 2) * 64 + lane];
    float2 v3 = f2[(size_t)(base + 3) * 64 + lane];
    float p0 = fmaf(v0.x, wv.x, v0.y * wv.y);
    float p1 = fmaf(v1.x, wv.x, v1.y * wv.y);
    float p2 = fmaf(v2.x, wv.x, v2.y * wv.y);
    float p3 = fmaf(v3.x, wv.x, v3.y * wv.y);
    #pragma unroll
    for (int off = 32; off > 0; off >>= 1) {
        p0 += __shfl_xor(p0, off, 64);
        p1 += __shfl_xor(p1, off, 64);
        p2 += __shfl_xor(p2, off, 64);
        p3 += __shfl_xor(p3, off, 64);
    }
    float ws_sum = 0.f;
    if (lane < 4) {
        int atom = base + lane;
        float pk = p0;
        pk = (lane == 1) ? p1 : pk;
        pk = (lane == 2) ? p2 : pk;
        pk = (lane == 3) ? p3 : pk;
        pk += ztab[z[atom]];
        xqp[atom] = make_float4(xyz[3*atom], xyz[3*atom+1], xyz[3*atom+2], pk);
        ws_sum = pk;
    }
    ws_sum += __shfl_xor(ws_sum, 1, 64);
    ws_sum += __shfl_xor(ws_sum, 2, 64);

    __shared__ float lred[4];
    if (lane == 0) lred[wid] = ws_sum;
    __syncthreads();
    if (t == 0) qpart[b] = lred[0] + lred[1] + lred[2] + lred[3];
}

// ---------------- kernel B: pair energy, 2400 blocks @ full occupancy -------
// Block b: tile = b>>1 -> (bi,bj) triangular, s = b&1 -> 32-j sub-tile.
// 9.4 blocks/CU -> first round saturates the 32-wave/CU cap. Inner loop
// software-pipelined (prefetch 4, 4 accumulator chains); r via parallel
// sqrtf (off the rsq chain). No atomics/fences: plain eblk[b] store.
__global__ __launch_bounds__(256) void pair_kernel(
    const float4* __restrict__ xqp, const float* __restrict__ qpart,
    const float* __restrict__ total_charge,
    float* __restrict__ qout, float* __restrict__ eblk)
{
    int t = threadIdx.x, b = blockIdx.x;
    int lane = t & 63, wid = t >> 6;
    __shared__ float lred[4];
    __shared__ float4 sj[32];

    // charge correction from the 384 per-block partials
    float s = qpart[t];
    if (t < NPRED - 256) s += qpart[256 + t];
    #pragma unroll
    for (int off = 32; off > 0; off >>= 1)
        s += __shfl_xor(s, off, 64);
    if (lane == 0) lred[wid] = s;
    __syncthreads();
    float S = lred[0] + lred[1] + lred[2] + lred[3];
    float corr = (total_charge[0] - S) * (1.0f / (float)N_ATOMS);

    // decode triangular (bi, bj): bj in [4*bi, 96)
    int tile = b >> 1, sub = b & 1;
    int bi = 0, off = 0;
    while (tile >= off + (96 - 4 * bi)) { off += 96 - 4 * bi; ++bi; }
    int bj = 4 * bi + (tile - off);

    int gj0 = bj * 64 + sub * 32;
    if (t < 32) {
        float4 a = xqp[gj0 + t];
        a.w += corr;
        sj[t] = a;
    }
    int gi = bi * 256 + t;
    float4 pi = xqp[gi];
    float qi = pi.w + corr;
    if (bj == 4 * bi && sub == 0) qout[gi] = qi;   // one writer per i
    __syncthreads();

    int jthresh = gi - gj0;             // pair valid iff k > jthresh

    // software-pipelined loop: prefetch distance 4, 4 accumulator chains
    float4 c0 = sj[0], c1 = sj[1], c2 = sj[2], c3 = sj[3];
    float acc0 = 0.f, acc1 = 0.f, acc2 = 0.f, acc3 = 0.f;
    #pragma unroll
    for (int k = 0; k < 32; k += 4) {
        float4 n0, n1, n2, n3;
        if (k + 4 < 32) {
            n0 = sj[k+4]; n1 = sj[k+5]; n2 = sj[k+6]; n3 = sj[k+7];
        }
        {
            float dx = pi.x - c0.x, dy = pi.y - c0.y, dz = pi.z - c0.z;
            float r2 = fmaf(dx, dx, fmaf(dy, dy, dz * dz));
            bool m = (k > jthresh) && (r2 > 0.f);
            float r2s = m ? r2 : 1e8f;
            float qq  = m ? qi * c0.w : 0.f;
            float t2 = __builtin_amdgcn_rsqf(r2s);
            float r  = __builtin_amdgcn_sqrtf(r2s);        // parallel trans
            float u  = fmaf(r, 0.2f, -0.5f);
            u = fminf(fmaxf(u, 1e-3f), 0.999f);
            float d  = (u + u - 1.f) * __builtin_amdgcn_rcpf(fmaf(-u, u, u));
            float fs = __builtin_amdgcn_rcpf(1.f + __expf(d));
            float t1 = __builtin_amdgcn_rsqf(r2s + 1.f);
            acc0 = fmaf(qq, fmaf(fs, t1 - t2, t2), acc0);
        }
        {
            float dx = pi.x - c1.x, dy = pi.y - c1.y, dz = pi.z - c1.z;
            float r2 = fmaf(dx, dx, fmaf(dy, dy, dz * dz));
            bool m = (k + 1 > jthresh) && (r2 > 0.f);
            float r2s = m ? r2 : 1e8f;
            float qq  = m ? qi * c1.w : 0.f;
            float t2 = __builtin_amdgcn_rsqf(r2s);
            float r  = __builtin_amdgcn_sqrtf(r2s);
            float u  = fmaf(r, 0.2f, -0.5f);
            u = fminf(fmaxf(u, 1e-3f), 0.999f);
            float d  = (u + u - 1.f) * __builtin_amdgcn_rcpf(fmaf(-u, u, u));
            float fs = __builtin_amdgcn_rcpf(1.f + __expf(d));
            float t1 = __builtin_amdgcn_rsqf(r2s + 1.f);
            acc1 = fmaf(qq, fmaf(fs, t1 - t2, t2), acc1);
        }
        {
            float dx = pi.x - c2.x, dy = pi.y - c2.y, dz = pi.z - c2.z;
            float r2 = fmaf(dx, dx, fmaf(dy, dy, dz * dz));
            bool m = (k + 2 > jthresh) && (r2 > 0.f);
            float r2s = m ? r2 : 1e8f;
            float qq  = m ? qi * c2.w : 0.f;
            float t2 = __builtin_amdgcn_rsqf(r2s);
            float r  = __builtin_amdgcn_sqrtf(r2s);
            float u  = fmaf(r, 0.2f, -0.5f);
            u = fminf(fmaxf(u, 1e-3f), 0.999f);
            float d  = (u + u - 1.f) * __builtin_amdgcn_rcpf(fmaf(-u, u, u));
            float fs = __builtin_amdgcn_rcpf(1.f + __expf(d));
            float t1 = __builtin_amdgcn_rsqf(r2s + 1.f);
            acc2 = fmaf(qq, fmaf(fs, t1 - t2, t2), acc2);
        }
        {
            float dx = pi.x - c3.x, dy = pi.y - c3.y, dz = pi.z - c3.z;
            float r2 = fmaf(dx, dx, fmaf(dy, dy, dz * dz));
            bool m = (k + 3 > jthresh) && (r2 > 0.f);
            float r2s = m ? r2 : 1e8f;
            float qq  = m ? qi * c3.w : 0.f;
            float t2 = __builtin_amdgcn_rsqf(r2s);
            float r  = __builtin_amdgcn_sqrtf(r2s);
            float u  = fmaf(r, 0.2f, -0.5f);
            u = fminf(fmaxf(u, 1e-3f), 0.999f);
            float d  = (u + u - 1.f) * __builtin_amdgcn_rcpf(fmaf(-u, u, u));
            float fs = __builtin_amdgcn_rcpf(1.f + __expf(d));
            float t1 = __builtin_amdgcn_rsqf(r2s + 1.f);
            acc3 = fmaf(qq, fmaf(fs, t1 - t2, t2), acc3);
        }
        c0 = n0; c1 = n1; c2 = n2; c3 = n3;
    }
    float acc = (acc0 + acc1) + (acc2 + acc3);

    #pragma unroll
    for (int o2 = 32; o2 > 0; o2 >>= 1)
        acc += __shfl_down(acc, o2, 64);
    __syncthreads();                    // lred reuse
    if (lane == 0) lred[wid] = acc;
    __syncthreads();
    if (t == 0) eblk[b] = lred[0] + lred[1] + lred[2] + lred[3];
}

// ---------------- kernel C: finalize energy ---------------------------------
__global__ __launch_bounds__(256) void efin_kernel(
    const float* __restrict__ eblk, float* __restrict__ out0)
{
    int t = threadIdx.x;
    float e = 0.f;
    for (int k = t; k < NPAIRB; k += 256) e += eblk[k];
    #pragma unroll
    for (int o2 = 32; o2 > 0; o2 >>= 1)
        e += __shfl_down(e, o2, 64);
    __shared__ float wacc[4];
    if ((t & 63) == 0) wacc[t >> 6] = e;
    __syncthreads();
    if (t == 0) out0[0] = KE_KCAL * (wacc[0] + wacc[1] + wacc[2] + wacc[3]);
}

extern "C" void kernel_launch(void* const* d_in, const int* in_sizes, int n_in,
                              void* d_out, int out_size, void* d_ws, size_t ws_size,
                              hipStream_t stream) {
    const float* f    = (const float*)d_in[0];
    const int*   z    = (const int*)  d_in[1];
    const float* xyz  = (const float*)d_in[2];
    const float* qtot = (const float*)d_in[3];
    const float* w    = (const float*)d_in[4];
    const float* ztab = (const float*)d_in[5];
    float* out = (float*)d_out;            // out[0]=energy, out[1..N]=q

    // ws: [0, 1536) qpart[384] | [2048, 2048+9600) eblk[2400]
    //     [16384, +98304) xqp[N] float4   (no zeroing needed anywhere)
    char* wsb = (char*)d_ws;
    float*  qpart = (float*)(wsb + 0);
    float*  eblk  = (float*)(wsb + 2048);
    float4* xqp   = (float4*)(wsb + 16384);

    pred_kernel<<<NPRED, 256, 0, stream>>>(f, z, w, ztab, xyz, qpart, xqp);
    pair_kernel<<<NPAIRB, 256, 0, stream>>>(xqp, qpart, qtot, out + 1, eblk);
    efin_kernel<<<1, 256, 0, stream>>>(eblk, out);
}

// Round 14
// 85.782 us; speedup vs baseline: 1.0744x; 1.0744x over previous
//
#include <hip/hip_runtime.h>

#define KE_KCAL 332.0637f

constexpr int N_ATOMS = 6144;
constexpr int NREAL = 1200;             // triangular 256x64 tiles
constexpr int NPRED = 384;              // pred blocks (16 atoms each)

// ---------------- kernel A: pred + per-block sums + pack --------------------
// 384 blocks x 256 thr, 4 atoms/wave (proven body). Plain stores only.
__global__ __launch_bounds__(256) void pred_kernel(
    const float* __restrict__ f, const int* __restrict__ z,
    const float* __restrict__ w, const float* __restrict__ ztab,
    const float* __restrict__ xyz,
    float* __restrict__ qpart, float4* __restrict__ xqp)
{
    int t = threadIdx.x, b = blockIdx.x;
    int lane = t & 63, wid = t >> 6;

    int base = b * 16 + wid * 4;
    const float2* f2 = (const float2*)f;
    float2 wv = ((const float2*)w)[lane];
    float2 v0 = f2[(size_t)(base + 0) * 64 + lane];
    float2 v1 = f2[(size_t)(base + 1) * 64 + lane];
    float2 v2 = f2[(size_t)(base + 2) * 64 + lane];
    float2 v3 = f2[(size_t)(base + 3) * 64 + lane];
    float p0 = fmaf(v0.x, wv.x, v0.y * wv.y);
    float p1 = fmaf(v1.x, wv.x, v1.y * wv.y);
    float p2 = fmaf(v2.x, wv.x, v2.y * wv.y);
    float p3 = fmaf(v3.x, wv.x, v3.y * wv.y);
    #pragma unroll
    for (int off = 32; off > 0; off >>= 1) {
        p0 += __shfl_xor(p0, off, 64);
        p1 += __shfl_xor(p1, off, 64);
        p2 += __shfl_xor(p2, off, 64);
        p3 += __shfl_xor(p3, off, 64);
    }
    float ws_sum = 0.f;
    if (lane < 4) {
        int atom = base + lane;
        float pk = p0;
        pk = (lane == 1) ? p1 : pk;
        pk = (lane == 2) ? p2 : pk;
        pk = (lane == 3) ? p3 : pk;
        pk += ztab[z[atom]];
        xqp[atom] = make_float4(xyz[3*atom], xyz[3*atom+1], xyz[3*atom+2], pk);
        ws_sum = pk;
    }
    ws_sum += __shfl_xor(ws_sum, 1, 64);
    ws_sum += __shfl_xor(ws_sum, 2, 64);

    __shared__ float lred[4];
    if (lane == 0) lred[wid] = ws_sum;
    __syncthreads();
    if (t == 0) qpart[b] = lred[0] + lred[1] + lred[2] + lred[3];
}

// ---------------- kernel B: pair energy, poly switch ------------------------
// 1200 triangular blocks x 256 thr (R12 proven skeleton). Switch function
// replaced by an odd degree-7 poly in v = clamp(r/5 - 1, -0.5, 0.5):
//   fs = 0.5 - v*(2 - 6.5 v^2 + 12 v^4 - 8 v^6)
// Constraints h(+-1/2)=+-1/2, h'=h''=0 there => EXACT 0/1 saturation outside
// [2.5, 7.5] (same as the exp form); antisymmetric error (max ~0.02) cancels
// in the energy sum. Chain: rsq/sqrt/rsq all parallel; no rcp/exp chain.
__global__ __launch_bounds__(256) void pair_kernel(
    const float4* __restrict__ xqp, const float* __restrict__ qpart,
    const float* __restrict__ total_charge,
    float* __restrict__ qout, float* __restrict__ eblk)
{
    int t = threadIdx.x, b = blockIdx.x;
    int lane = t & 63, wid = t >> 6;
    __shared__ float lred[4];
    __shared__ float4 sj[64];

    // charge correction from the 384 per-block partials
    float s = qpart[t];
    if (t < NPRED - 256) s += qpart[256 + t];
    #pragma unroll
    for (int off = 32; off > 0; off >>= 1)
        s += __shfl_xor(s, off, 64);
    if (lane == 0) lred[wid] = s;
    __syncthreads();
    float S = lred[0] + lred[1] + lred[2] + lred[3];
    float corr = (total_charge[0] - S) * (1.0f / (float)N_ATOMS);

    // decode triangular (bi, bj): bj in [4*bi, 96)
    int bi = 0, off = 0;
    while (b >= off + (96 - 4 * bi)) { off += 96 - 4 * bi; ++bi; }
    int bj = 4 * bi + (b - off);

    int gj0 = bj * 64;
    if (t < 64) {
        float4 a = xqp[gj0 + t];
        a.w += corr;
        sj[t] = a;
    }
    int gi = bi * 256 + t;
    float4 pi = xqp[gi];
    float qi = pi.w + corr;
    if (bj == 4 * bi) qout[gi] = qi;
    __syncthreads();

    int jthresh = gi - gj0;             // pair valid iff k > jthresh

    // software-pipelined loop: prefetch distance 4, 4 accumulator chains
    float4 c0 = sj[0], c1 = sj[1], c2 = sj[2], c3 = sj[3];
    float acc0 = 0.f, acc1 = 0.f, acc2 = 0.f, acc3 = 0.f;
    #pragma unroll
    for (int k = 0; k < 64; k += 4) {
        float4 n0, n1, n2, n3;
        if (k + 4 < 64) {
            n0 = sj[k+4]; n1 = sj[k+5]; n2 = sj[k+6]; n3 = sj[k+7];
        }
        {
            float dx = pi.x - c0.x, dy = pi.y - c0.y, dz = pi.z - c0.z;
            float r2 = fmaf(dx, dx, fmaf(dy, dy, dz * dz));
            bool m = (k > jthresh) && (r2 > 0.f);
            float r2s = m ? r2 : 1e8f;
            float qq  = m ? qi * c0.w : 0.f;
            float t2 = __builtin_amdgcn_rsqf(r2s);             // 1/r
            float r  = __builtin_amdgcn_sqrtf(r2s);            // parallel
            float t1 = __builtin_amdgcn_rsqf(r2s + 1.f);       // parallel
            float v  = fmaf(r, 0.2f, -1.0f);                   // (r-5)/5
            v = fminf(fmaxf(v, -0.5f), 0.5f);                  // exact sat
            float v2 = v * v;
            float p  = fmaf(v2, fmaf(v2, fmaf(v2, -8.f, 12.f), -6.5f), 2.f);
            float fs = fmaf(-v, p, 0.5f);
            acc0 = fmaf(qq, fmaf(fs, t1 - t2, t2), acc0);
        }
        {
            float dx = pi.x - c1.x, dy = pi.y - c1.y, dz = pi.z - c1.z;
            float r2 = fmaf(dx, dx, fmaf(dy, dy, dz * dz));
            bool m = (k + 1 > jthresh) && (r2 > 0.f);
            float r2s = m ? r2 : 1e8f;
            float qq  = m ? qi * c1.w : 0.f;
            float t2 = __builtin_amdgcn_rsqf(r2s);
            float r  = __builtin_amdgcn_sqrtf(r2s);
            float t1 = __builtin_amdgcn_rsqf(r2s + 1.f);
            float v  = fmaf(r, 0.2f, -1.0f);
            v = fminf(fmaxf(v, -0.5f), 0.5f);
            float v2 = v * v;
            float p  = fmaf(v2, fmaf(v2, fmaf(v2, -8.f, 12.f), -6.5f), 2.f);
            float fs = fmaf(-v, p, 0.5f);
            acc1 = fmaf(qq, fmaf(fs, t1 - t2, t2), acc1);
        }
        {
            float dx = pi.x - c2.x, dy = pi.y - c2.y, dz = pi.z - c2.z;
            float r2 = fmaf(dx, dx, fmaf(dy, dy, dz * dz));
            bool m = (k + 2 > jthresh) && (r2 > 0.f);
            float r2s = m ? r2 : 1e8f;
            float qq  = m ? qi * c2.w : 0.f;
            float t2 = __builtin_amdgcn_rsqf(r2s);
            float r  = __builtin_amdgcn_sqrtf(r2s);
            float t1 = __builtin_amdgcn_rsqf(r2s + 1.f);
            float v  = fmaf(r, 0.2f, -1.0f);
            v = fminf(fmaxf(v, -0.5f), 0.5f);
            float v2 = v * v;
            float p  = fmaf(v2, fmaf(v2, fmaf(v2, -8.f, 12.f), -6.5f), 2.f);
            float fs = fmaf(-v, p, 0.5f);
            acc2 = fmaf(qq, fmaf(fs, t1 - t2, t2), acc2);
        }
        {
            float dx = pi.x - c3.x, dy = pi.y - c3.y, dz = pi.z - c3.z;
            float r2 = fmaf(dx, dx, fmaf(dy, dy, dz * dz));
            bool m = (k + 3 > jthresh) && (r2 > 0.f);
            float r2s = m ? r2 : 1e8f;
            float qq  = m ? qi * c3.w : 0.f;
            float t2 = __builtin_amdgcn_rsqf(r2s);
            float r  = __builtin_amdgcn_sqrtf(r2s);
            float t1 = __builtin_amdgcn_rsqf(r2s + 1.f);
            float v  = fmaf(r, 0.2f, -1.0f);
            v = fminf(fmaxf(v, -0.5f), 0.5f);
            float v2 = v * v;
            float p  = fmaf(v2, fmaf(v2, fmaf(v2, -8.f, 12.f), -6.5f), 2.f);
            float fs = fmaf(-v, p, 0.5f);
            acc3 = fmaf(qq, fmaf(fs, t1 - t2, t2), acc3);
        }
        c0 = n0; c1 = n1; c2 = n2; c3 = n3;
    }
    float acc = (acc0 + acc1) + (acc2 + acc3);

    #pragma unroll
    for (int o2 = 32; o2 > 0; o2 >>= 1)
        acc += __shfl_down(acc, o2, 64);
    __syncthreads();                    // lred reuse
    if (lane == 0) lred[wid] = acc;
    __syncthreads();
    if (t == 0) eblk[b] = lred[0] + lred[1] + lred[2] + lred[3];
}

// ---------------- kernel C: finalize energy ---------------------------------
__global__ __launch_bounds__(256) void efin_kernel(
    const float* __restrict__ eblk, float* __restrict__ out0)
{
    int t = threadIdx.x;
    float e = 0.f;
    for (int k = t; k < NREAL; k += 256) e += eblk[k];
    #pragma unroll
    for (int o2 = 32; o2 > 0; o2 >>= 1)
        e += __shfl_down(e, o2, 64);
    __shared__ float wacc[4];
    if ((t & 63) == 0) wacc[t >> 6] = e;
    __syncthreads();
    if (t == 0) out0[0] = KE_KCAL * (wacc[0] + wacc[1] + wacc[2] + wacc[3]);
}

extern "C" void kernel_launch(void* const* d_in, const int* in_sizes, int n_in,
                              void* d_out, int out_size, void* d_ws, size_t ws_size,
                              hipStream_t stream) {
    const float* f    = (const float*)d_in[0];
    const int*   z    = (const int*)  d_in[1];
    const float* xyz  = (const float*)d_in[2];
    const float* qtot = (const float*)d_in[3];
    const float* w    = (const float*)d_in[4];
    const float* ztab = (const float*)d_in[5];
    float* out = (float*)d_out;            // out[0]=energy, out[1..N]=q

    // ws: [0, 1536) qpart[384] | [2048, 2048+4800) eblk[1200]
    //     [16384, +98304) xqp[N] float4   (no zeroing needed anywhere)
    char* wsb = (char*)d_ws;
    float*  qpart = (float*)(wsb + 0);
    float*  eblk  = (float*)(wsb + 2048);
    float4* xqp   = (float4*)(wsb + 16384);

    pred_kernel<<<NPRED, 256, 0, stream>>>(f, z, w, ztab, xyz, qpart, xqp);
    pair_kernel<<<NREAL, 256, 0, stream>>>(xqp, qpart, qtot, out + 1, eblk);
    efin_kernel<<<1, 256, 0, stream>>>(eblk, out);
}

// Round 15
// 83.788 us; speedup vs baseline: 1.0999x; 1.0238x over previous
//
#include <hip/hip_runtime.h>

#define KE_KCAL 332.0637f

constexpr int N_ATOMS = 6144;
constexpr int NREAL = 1200;             // triangular 256x64 tiles
constexpr int NPRED = 384;              // pred blocks (16 atoms each)

// ---------------- kernel A: pred + per-block sums + pack --------------------
__global__ __launch_bounds__(256) void pred_kernel(
    const float* __restrict__ f, const int* __restrict__ z,
    const float* __restrict__ w, const float* __restrict__ ztab,
    const float* __restrict__ xyz,
    float* __restrict__ qpart, float4* __restrict__ xqp)
{
    int t = threadIdx.x, b = blockIdx.x;
    int lane = t & 63, wid = t >> 6;

    int base = b * 16 + wid * 4;
    const float2* f2 = (const float2*)f;
    float2 wv = ((const float2*)w)[lane];
    float2 v0 = f2[(size_t)(base + 0) * 64 + lane];
    float2 v1 = f2[(size_t)(base + 1) * 64 + lane];
    float2 v2 = f2[(size_t)(base + 2) * 64 + lane];
    float2 v3 = f2[(size_t)(base + 3) * 64 + lane];
    float p0 = fmaf(v0.x, wv.x, v0.y * wv.y);
    float p1 = fmaf(v1.x, wv.x, v1.y * wv.y);
    float p2 = fmaf(v2.x, wv.x, v2.y * wv.y);
    float p3 = fmaf(v3.x, wv.x, v3.y * wv.y);
    #pragma unroll
    for (int off = 32; off > 0; off >>= 1) {
        p0 += __shfl_xor(p0, off, 64);
        p1 += __shfl_xor(p1, off, 64);
        p2 += __shfl_xor(p2, off, 64);
        p3 += __shfl_xor(p3, off, 64);
    }
    float ws_sum = 0.f;
    if (lane < 4) {
        int atom = base + lane;
        float pk = p0;
        pk = (lane == 1) ? p1 : pk;
        pk = (lane == 2) ? p2 : pk;
        pk = (lane == 3) ? p3 : pk;
        pk += ztab[z[atom]];
        xqp[atom] = make_float4(xyz[3*atom], xyz[3*atom+1], xyz[3*atom+2], pk);
        ws_sum = pk;
    }
    ws_sum += __shfl_xor(ws_sum, 1, 64);
    ws_sum += __shfl_xor(ws_sum, 2, 64);

    __shared__ float lred[4];
    if (lane == 0) lred[wid] = ws_sum;
    __syncthreads();
    if (t == 0) qpart[b] = lred[0] + lred[1] + lred[2] + lred[3];
}

// ---------------- pair term: ONE transcendental per pair --------------------
// term = rsq(x + fs(x)), x = r^2.
//   fs=0 -> 1/r exact (r>=7.5); fs=1 -> 1/sqrt(r2+1) exact (r<=2.5);
//   mid: interp-inside-rsq error <= 2e-5. fs(x) = h(v(u)):
//   u = clamp((x-31.25)/50, +-1/2); v(u) monotone cubic, v(+-1/2)=+-1/2 exact;
//   h = odd deg-7 poly (R14-proven), h(+-1/2) = 1/0 exact, h'=h''=0 there.
//   => saturation outside [2.5, 7.5] A is EXACT; |fs err| <= 0.026 inside.
template<bool DIAG>
__device__ __forceinline__ float pair_term(
    const float4& c, const float4& pi, float qi, int k, int jthresh)
{
    float dx = pi.x - c.x, dy = pi.y - c.y, dz = pi.z - c.z;
    float x  = fmaf(dx, dx, fmaf(dy, dy, dz * dz));
    bool m = (!DIAG || (k > jthresh)) && (x > 0.f);
    float qq = m ? qi * c.w : 0.f;
    float u = fmaf(x, 0.02f, -0.625f);                 // (x-31.25)/50
    u = fminf(fmaxf(u, -0.5f), 0.5f);
    float v = fmaf(u, fmaf(u, fmaf(u, 0.333856f, -0.472136f),
                           0.916536f), 0.118034f);    // v(+-.5)=+-.5 exact
    float v2 = v * v;
    float p  = fmaf(v2, fmaf(v2, fmaf(v2, -8.f, 12.f), -6.5f), 2.f);
    float arg = fmaf(-v, p, x + 0.5f);                 // x + fs
    return qq * __builtin_amdgcn_rsqf(arg);
}

// ---------------- kernel B: pair energy -------------------------------------
// 1200 triangular blocks x 256 thr (R12/R14 proven skeleton). Software-
// pipelined (prefetch 4, 4 accumulator chains). Off-diagonal blocks (92%)
// use the maskless template instance (wave-uniform selection).
__global__ __launch_bounds__(256) void pair_kernel(
    const float4* __restrict__ xqp, const float* __restrict__ qpart,
    const float* __restrict__ total_charge,
    float* __restrict__ qout, float* __restrict__ eblk)
{
    int t = threadIdx.x, b = blockIdx.x;
    int lane = t & 63, wid = t >> 6;
    __shared__ float lred[4];
    __shared__ float4 sj[64];

    // charge correction from the 384 per-block partials
    float s = qpart[t];
    if (t < NPRED - 256) s += qpart[256 + t];
    #pragma unroll
    for (int off = 32; off > 0; off >>= 1)
        s += __shfl_xor(s, off, 64);
    if (lane == 0) lred[wid] = s;
    __syncthreads();
    float S = lred[0] + lred[1] + lred[2] + lred[3];
    float corr = (total_charge[0] - S) * (1.0f / (float)N_ATOMS);

    // decode triangular (bi, bj): bj in [4*bi, 96)
    int bi = 0, off = 0;
    while (b >= off + (96 - 4 * bi)) { off += 96 - 4 * bi; ++bi; }
    int bj = 4 * bi + (b - off);

    int gj0 = bj * 64;
    if (t < 64) {
        float4 a = xqp[gj0 + t];
        a.w += corr;
        sj[t] = a;
    }
    int gi = bi * 256 + t;
    float4 pi = xqp[gi];
    float qi = pi.w + corr;
    if (bj == 4 * bi) qout[gi] = qi;
    __syncthreads();

    int jthresh = gi - gj0;             // pair valid iff k > jthresh
    bool diag = (bj - 4 * bi) < 4;      // i/j ranges overlap (wave-uniform)

    float acc0 = 0.f, acc1 = 0.f, acc2 = 0.f, acc3 = 0.f;

#define PAIR_LOOP(DIAG_FLAG)                                                  \
    {                                                                         \
        float4 c0 = sj[0], c1 = sj[1], c2 = sj[2], c3 = sj[3];                \
        _Pragma("unroll")                                                     \
        for (int k = 0; k < 64; k += 4) {                                     \
            float4 n0, n1, n2, n3;                                            \
            if (k + 4 < 64) {                                                 \
                n0 = sj[k+4]; n1 = sj[k+5]; n2 = sj[k+6]; n3 = sj[k+7];       \
            }                                                                 \
            acc0 += pair_term<DIAG_FLAG>(c0, pi, qi, k,     jthresh);         \
            acc1 += pair_term<DIAG_FLAG>(c1, pi, qi, k + 1, jthresh);         \
            acc2 += pair_term<DIAG_FLAG>(c2, pi, qi, k + 2, jthresh);         \
            acc3 += pair_term<DIAG_FLAG>(c3, pi, qi, k + 3, jthresh);         \
            c0 = n0; c1 = n1; c2 = n2; c3 = n3;                               \
        }                                                                     \
    }

    if (diag) PAIR_LOOP(true) else PAIR_LOOP(false)
#undef PAIR_LOOP

    float acc = (acc0 + acc1) + (acc2 + acc3);

    #pragma unroll
    for (int o2 = 32; o2 > 0; o2 >>= 1)
        acc += __shfl_down(acc, o2, 64);
    __syncthreads();                    // lred reuse
    if (lane == 0) lred[wid] = acc;
    __syncthreads();
    if (t == 0) eblk[b] = lred[0] + lred[1] + lred[2] + lred[3];
}

// ---------------- kernel C: finalize energy ---------------------------------
__global__ __launch_bounds__(256) void efin_kernel(
    const float* __restrict__ eblk, float* __restrict__ out0)
{
    int t = threadIdx.x;
    float e = 0.f;
    for (int k = t; k < NREAL; k += 256) e += eblk[k];
    #pragma unroll
    for (int o2 = 32; o2 > 0; o2 >>= 1)
        e += __shfl_down(e, o2, 64);
    __shared__ float wacc[4];
    if ((t & 63) == 0) wacc[t >> 6] = e;
    __syncthreads();
    if (t == 0) out0[0] = KE_KCAL * (wacc[0] + wacc[1] + wacc[2] + wacc[3]);
}

extern "C" void kernel_launch(void* const* d_in, const int* in_sizes, int n_in,
                              void* d_out, int out_size, void* d_ws, size_t ws_size,
                              hipStream_t stream) {
    const float* f    = (const float*)d_in[0];
    const int*   z    = (const int*)  d_in[1];
    const float* xyz  = (const float*)d_in[2];
    const float* qtot = (const float*)d_in[3];
    const float* w    = (const float*)d_in[4];
    const float* ztab = (const float*)d_in[5];
    float* out = (float*)d_out;            // out[0]=energy, out[1..N]=q

    // ws: [0, 1536) qpart[384] | [2048, 2048+4800) eblk[1200]
    //     [16384, +98304) xqp[N] float4   (no zeroing needed anywhere)
    char* wsb = (char*)d_ws;
    float*  qpart = (float*)(wsb + 0);
    float*  eblk  = (float*)(wsb + 2048);
    float4* xqp   = (float4*)(wsb + 16384);

    pred_kernel<<<NPRED, 256, 0, stream>>>(f, z, w, ztab, xyz, qpart, xqp);
    pair_kernel<<<NREAL, 256, 0, stream>>>(xqp, qpart, qtot, out + 1, eblk);
    efin_kernel<<<1, 256, 0, stream>>>(eblk, out);
}

// Round 16
// 82.757 us; speedup vs baseline: 1.1137x; 1.0125x over previous
//
#include <hip/hip_runtime.h>

#define KE_KCAL 332.0637f

constexpr int N_ATOMS = 6144;
constexpr int NREAL = 1200;             // triangular 256x64 tiles
constexpr int NPRED = 384;              // pred blocks (16 atoms each)

typedef float v2f __attribute__((ext_vector_type(2)));
typedef float v4f __attribute__((ext_vector_type(4)));

// ---------------- kernel A: pred + per-block sums + pack --------------------
__global__ __launch_bounds__(256) void pred_kernel(
    const float* __restrict__ f, const int* __restrict__ z,
    const float* __restrict__ w, const float* __restrict__ ztab,
    const float* __restrict__ xyz,
    float* __restrict__ qpart, float4* __restrict__ xqp)
{
    int t = threadIdx.x, b = blockIdx.x;
    int lane = t & 63, wid = t >> 6;

    int base = b * 16 + wid * 4;
    const float2* f2 = (const float2*)f;
    float2 wv = ((const float2*)w)[lane];
    float2 v0 = f2[(size_t)(base + 0) * 64 + lane];
    float2 v1 = f2[(size_t)(base + 1) * 64 + lane];
    float2 v2 = f2[(size_t)(base + 2) * 64 + lane];
    float2 v3 = f2[(size_t)(base + 3) * 64 + lane];
    float p0 = fmaf(v0.x, wv.x, v0.y * wv.y);
    float p1 = fmaf(v1.x, wv.x, v1.y * wv.y);
    float p2 = fmaf(v2.x, wv.x, v2.y * wv.y);
    float p3 = fmaf(v3.x, wv.x, v3.y * wv.y);
    #pragma unroll
    for (int off = 32; off > 0; off >>= 1) {
        p0 += __shfl_xor(p0, off, 64);
        p1 += __shfl_xor(p1, off, 64);
        p2 += __shfl_xor(p2, off, 64);
        p3 += __shfl_xor(p3, off, 64);
    }
    float ws_sum = 0.f;
    if (lane < 4) {
        int atom = base + lane;
        float pk = p0;
        pk = (lane == 1) ? p1 : pk;
        pk = (lane == 2) ? p2 : pk;
        pk = (lane == 3) ? p3 : pk;
        pk += ztab[z[atom]];
        xqp[atom] = make_float4(xyz[3*atom], xyz[3*atom+1], xyz[3*atom+2], pk);
        ws_sum = pk;
    }
    ws_sum += __shfl_xor(ws_sum, 1, 64);
    ws_sum += __shfl_xor(ws_sum, 2, 64);

    __shared__ float lred[4];
    if (lane == 0) lred[wid] = ws_sum;
    __syncthreads();
    if (t == 0) qpart[b] = lred[0] + lred[1] + lred[2] + lred[3];
}

// ---------------- packed pair term: 2 pairs per VOP3P stream ----------------
// term = rsq(x + fs(x)), x = r^2 (R15-proven, absmax 3.8e-6).
// fs = h(v(u)): u = clamp((x-31.25)/50, +-1/2); cubic v; odd deg-7 h.
// Saturation outside [2.5, 7.5] A exact. All fma/mul/add packed (v_pk_*);
// clamp + rsq scalarize onto the vector halves (no repack movs).
template<bool DIAG>
__device__ __forceinline__ v2f pair2(v2f jx, v2f jy, v2f jz, v2f jq,
                                     float px, float py, float pz, float qi,
                                     int k0, int jthresh)
{
    v2f dx = px - jx, dy = py - jy, dz = pz - jz;
    v2f x  = __builtin_elementwise_fma(dx, dx,
             __builtin_elementwise_fma(dy, dy, dz * dz));
    v2f qq = qi * jq;
    if (DIAG) {
        qq.x = ((k0     > jthresh) && (x.x > 0.f)) ? qq.x : 0.f;
        qq.y = ((k0 + 1 > jthresh) && (x.y > 0.f)) ? qq.y : 0.f;
    }
    v2f u = __builtin_elementwise_fma(x, (v2f)(0.02f), (v2f)(-0.625f));
    u = __builtin_elementwise_min(__builtin_elementwise_max(u, (v2f)(-0.5f)),
                                  (v2f)(0.5f));
    v2f v = __builtin_elementwise_fma(u,
              __builtin_elementwise_fma(u,
                __builtin_elementwise_fma(u, (v2f)(0.333856f),
                                          (v2f)(-0.472136f)),
                (v2f)(0.916536f)),
              (v2f)(0.118034f));
    v2f v2 = v * v;
    v2f p  = __builtin_elementwise_fma(v2,
               __builtin_elementwise_fma(v2,
                 __builtin_elementwise_fma(v2, (v2f)(-8.f), (v2f)(12.f)),
                 (v2f)(-6.5f)),
               (v2f)(2.f));
    v2f arg = __builtin_elementwise_fma(-v, p, x + 0.5f);   // x + fs
    v2f rs;
    rs.x = __builtin_amdgcn_rsqf(arg.x);
    rs.y = __builtin_amdgcn_rsqf(arg.y);
    return qq * rs;
}

// ---------------- kernel B: pair energy, packed-math loop -------------------
// 1200 triangular blocks x 256 thr (R12/R15 proven skeleton). j-tile staged
// SoA in LDS so v4f loads give packed pairs in adjacent VGPRs. Software-
// pipelined (prefetch 4 j's, 2 packed accumulator chains).
__global__ __launch_bounds__(256) void pair_kernel(
    const float4* __restrict__ xqp, const float* __restrict__ qpart,
    const float* __restrict__ total_charge,
    float* __restrict__ qout, float* __restrict__ eblk)
{
    int t = threadIdx.x, b = blockIdx.x;
    int lane = t & 63, wid = t >> 6;
    __shared__ float lred[4];
    __shared__ __align__(16) float sx[64], sy[64], sz[64], sq[64];

    // charge correction from the 384 per-block partials
    float s = qpart[t];
    if (t < NPRED - 256) s += qpart[256 + t];
    #pragma unroll
    for (int off = 32; off > 0; off >>= 1)
        s += __shfl_xor(s, off, 64);
    if (lane == 0) lred[wid] = s;
    __syncthreads();
    float S = lred[0] + lred[1] + lred[2] + lred[3];
    float corr = (total_charge[0] - S) * (1.0f / (float)N_ATOMS);

    // decode triangular (bi, bj): bj in [4*bi, 96)
    int bi = 0, off = 0;
    while (b >= off + (96 - 4 * bi)) { off += 96 - 4 * bi; ++bi; }
    int bj = 4 * bi + (b - off);

    int gj0 = bj * 64;
    if (t < 64) {
        float4 a = xqp[gj0 + t];
        sx[t] = a.x; sy[t] = a.y; sz[t] = a.z; sq[t] = a.w + corr;
    }
    int gi = bi * 256 + t;
    float4 pi = xqp[gi];
    float qi = pi.w + corr;
    if (bj == 4 * bi) qout[gi] = qi;
    __syncthreads();

    int jthresh = gi - gj0;             // pair valid iff k > jthresh
    bool diag = (bj - 4 * bi) < 4;      // i/j ranges overlap (wave-uniform)

    v2f accA = {0.f, 0.f}, accB = {0.f, 0.f};

#define PAIR_LOOP(DIAG_FLAG)                                                  \
    {                                                                         \
        v4f cx = *(const v4f*)&sx[0], cy = *(const v4f*)&sy[0];               \
        v4f cz = *(const v4f*)&sz[0], cq = *(const v4f*)&sq[0];               \
        _Pragma("unroll")                                                     \
        for (int k = 0; k < 64; k += 4) {                                     \
            v4f nx, ny, nz, nq;                                               \
            if (k + 4 < 64) {                                                 \
                nx = *(const v4f*)&sx[k+4]; ny = *(const v4f*)&sy[k+4];       \
                nz = *(const v4f*)&sz[k+4]; nq = *(const v4f*)&sq[k+4];       \
            }                                                                 \
            accA += pair2<DIAG_FLAG>(cx.lo, cy.lo, cz.lo, cq.lo,              \
                                     pi.x, pi.y, pi.z, qi, k,     jthresh);   \
            accB += pair2<DIAG_FLAG>(cx.hi, cy.hi, cz.hi, cq.hi,              \
                                     pi.x, pi.y, pi.z, qi, k + 2, jthresh);   \
            cx = nx; cy = ny; cz = nz; cq = nq;                               \
        }                                                                     \
    }

    if (diag) PAIR_LOOP(true) else PAIR_LOOP(false)
#undef PAIR_LOOP

    float acc = (accA.x + accA.y) + (accB.x + accB.y);

    #pragma unroll
    for (int o2 = 32; o2 > 0; o2 >>= 1)
        acc += __shfl_down(acc, o2, 64);
    __syncthreads();                    // lred reuse
    if (lane == 0) lred[wid] = acc;
    __syncthreads();
    if (t == 0) eblk[b] = lred[0] + lred[1] + lred[2] + lred[3];
}

// ---------------- kernel C: finalize energy ---------------------------------
__global__ __launch_bounds__(256) void efin_kernel(
    const float* __restrict__ eblk, float* __restrict__ out0)
{
    int t = threadIdx.x;
    float e = 0.f;
    for (int k = t; k < NREAL; k += 256) e += eblk[k];
    #pragma unroll
    for (int o2 = 32; o2 > 0; o2 >>= 1)
        e += __shfl_down(e, o2, 64);
    __shared__ float wacc[4];
    if ((t & 63) == 0) wacc[t >> 6] = e;
    __syncthreads();
    if (t == 0) out0[0] = KE_KCAL * (wacc[0] + wacc[1] + wacc[2] + wacc[3]);
}

extern "C" void kernel_launch(void* const* d_in, const int* in_sizes, int n_in,
                              void* d_out, int out_size, void* d_ws, size_t ws_size,
                              hipStream_t stream) {
    const float* f    = (const float*)d_in[0];
    const int*   z    = (const int*)  d_in[1];
    const float* xyz  = (const float*)d_in[2];
    const float* qtot = (const float*)d_in[3];
    const float* w    = (const float*)d_in[4];
    const float* ztab = (const float*)d_in[5];
    float* out = (float*)d_out;            // out[0]=energy, out[1..N]=q

    // ws: [0, 1536) qpart[384] | [2048, 2048+4800) eblk[1200]
    //     [16384, +98304) xqp[N] float4   (no zeroing needed anywhere)
    char* wsb = (char*)d_ws;
    float*  qpart = (float*)(wsb + 0);
    float*  eblk  = (float*)(wsb + 2048);
    float4* xqp   = (float4*)(wsb + 16384);

    pred_kernel<<<NPRED, 256, 0, stream>>>(f, z, w, ztab, xyz, qpart, xqp);
    pair_kernel<<<NREAL, 256, 0, stream>>>(xqp, qpart, qtot, out + 1, eblk);
    efin_kernel<<<1, 256, 0, stream>>>(eblk, out);
}